// Round 1
// 156.698 us; speedup vs baseline: 1.0512x; 1.0512x over previous
//
#include <hip/hip_runtime.h>
#include <hip/hip_bf16.h>

typedef __attribute__((ext_vector_type(4))) float f32x4;
typedef __attribute__((ext_vector_type(8))) short bf16x8;
typedef __attribute__((ext_vector_type(4))) short s16x4;
typedef __attribute__((ext_vector_type(4))) unsigned int u32x4;

#define DEV static __device__ __forceinline__

// fp32 -> bf16 round-to-nearest-even (finite values only)
DEV unsigned short f2b(float f) {
  union { float f; unsigned int u; } v; v.f = f;
  unsigned int u = v.u;
  return (unsigned short)((u + 0x7fffu + ((u >> 16) & 1u)) >> 16);
}

// async global->LDS, 16B per lane; lds base wave-uniform, lanes land at base + lane*16
DEV void gll16(const void* g, void* l) {
  __builtin_amdgcn_global_load_lds((__attribute__((address_space(1))) void*)g,
                                   (__attribute__((address_space(3))) void*)l,
                                   16, 0, 0);
}

// ---------------------------------------------------------------------------
// prep: fp32 -> bf16 conversion + weight repack.
// Round 4: weight transposes now LDS-tiled (64x64) so global reads AND writes
// are coalesced (was: stride-256B reads for Wt, stride-2KB reads for WoT).
// Blocks 0..8191: x conversion (f32x4 -> s16x4, coalesced, unchanged).
// Blocks 8192..8383: Wt tiles (3 proj x 8 heads x 8 c-blocks).
// Blocks 8384..8447: WoT tiles (8 x 8 of 64x64).
// ---------------------------------------------------------------------------
__global__ __launch_bounds__(256) void prep(const float* __restrict__ x,
                                            const float* __restrict__ Wq,
                                            const float* __restrict__ Wk,
                                            const float* __restrict__ Wv,
                                            const float* __restrict__ Wo,
                                            unsigned short* __restrict__ xb,
                                            unsigned short* __restrict__ Wt,
                                            unsigned short* __restrict__ WoT) {
  const int bid = blockIdx.x;
  if (bid < 8192) {                                    // x: 8388608 elems / 4
    int id = bid * 256 + threadIdx.x;
    f32x4 v = *(const f32x4*)(x + (long)id * 4);
    s16x4 o;
    o.x = (short)f2b(v.x); o.y = (short)f2b(v.y);
    o.z = (short)f2b(v.z); o.w = (short)f2b(v.w);
    *(s16x4*)(xb + (long)id * 4) = o;
    return;
  }

  // 64x64 transpose tile via LDS; u32 elements, +1 pad => conflict-free
  // both phases (bank = (row + col) % 32, distinct across a wave).
  __shared__ unsigned int L[64 * 65];
  const int tx = threadIdx.x & 63;     // fast index (coalesced axis)
  const int ty = threadIdx.x >> 6;     // wave id: 4 rows in flight

  int tb = bid - 8192;
  if (tb < 192) {
    // Wt[n][c] = W[h][c][d], n = proj*512 + h*64 + d. Tile: full d (64) x 64 c.
    int proj = tb >> 6, h = (tb >> 3) & 7, c0 = (tb & 7) << 6;
    const float* W = (proj == 0) ? Wq : ((proj == 1) ? Wk : Wv);
    const float* base = W + (long)h * 32768 + (long)c0 * 64;  // [c][d]
#pragma unroll
    for (int i = 0; i < 16; i++) {
      int c = ty + i * 4;                               // per-wave row; tx = d
      L[tx * 65 + c] = f2b(base[(long)c * 64 + tx]);    // L[d][c]
    }
    __syncthreads();
    unsigned short* out = Wt + ((long)(proj * 512 + h * 64)) * 512 + c0;
#pragma unroll
    for (int i = 0; i < 16; i++) {
      int d = ty + i * 4;                               // tx = c_local
      out[(long)d * 512 + tx] = (unsigned short)L[d * 65 + tx];
    }
  } else {
    // WoT[n][c] = Wo[c][n]. Tile 64 n x 64 c.
    int t = tb - 192;
    int n0 = (t >> 3) << 6, c0 = (t & 7) << 6;
#pragma unroll
    for (int i = 0; i < 16; i++) {
      int c = ty + i * 4;                               // tx = n_local
      L[tx * 65 + c] = f2b(Wo[(long)(c0 + c) * 512 + n0 + tx]);  // L[n][c]
    }
    __syncthreads();
    unsigned short* out = WoT + (long)n0 * 512 + c0;
#pragma unroll
    for (int i = 0; i < 16; i++) {
      int n = ty + i * 4;                               // tx = c_local
      out[(long)n * 512 + tx] = (unsigned short)L[n * 65 + tx];
    }
  }
}

// ---------------------------------------------------------------------------
// C[M x N] = A[M x 512] * BT[N x 512]^T   (bf16 in, fp32 accum)
// BK=64, 128x128 tile, 32 KB LDS, global-side XOR swizzle for gll16.
// Round 4: 1-D grid + bijective XCD swizzle (T1/m204), bn-FAST within each
// XCD chunk. Consecutive co-XCD blocks now share the same 128-row A panel
// (16 A panels = 2 MB + full B <= 1.5 MB per XCD L2), so A is fetched from
// HBM/L3 once instead of once per bn-sweep (was ~200 MB L3 traffic in gemm1).
// ---------------------------------------------------------------------------
template <int F32OUT>
__global__ __launch_bounds__(256, 2) void gemm_bt(const unsigned short* __restrict__ A,
                                                  const unsigned short* __restrict__ BT,
                                                  void* __restrict__ Cv,
                                                  int N) {
  const int K = 512;
  __shared__ unsigned short As[128 * 64];
  __shared__ unsigned short Bs[128 * 64];

  const int tid = threadIdx.x;
  const int wave = tid >> 6, lane = tid & 63;
  const int quad = lane >> 4, l16 = lane & 15;
  const int wm = wave >> 1, wn = wave & 1;

  // bijective XCD swizzle: chunk of nwg/8 consecutive tiles per XCD,
  // bn-fast tile order inside the chunk (A-panel reuse within one L2).
  const int NB = N >> 7;
  const int nwg = gridDim.x;                     // multiple of 8 for our launches
  const int q = nwg >> 3, r = nwg & 7;
  const int xcd = blockIdx.x & 7, ci = blockIdx.x >> 3;
  const int wg = (xcd < r ? xcd * (q + 1) : r * (q + 1) + (xcd - r) * q) + ci;
  const int bn = wg % NB;
  const int bm = wg / NB;

  // staging: 8-row segments of 64 cols; lane i: row i>>3, fetches global
  // col-group (i&7) ^ (row&7), lands at lds cg i&7.
  const int srow = lane >> 3;
  const int scol = ((lane & 7) ^ srow) * 8;

  f32x4 acc[4][4] = {};

  for (int kk = 0; kk < K; kk += 64) {
    __syncthreads();  // previous iteration's LDS reads complete
#pragma unroll
    for (int s = 0; s < 4; s++) {
      int seg = wave * 4 + s;                       // 16 segs x 8 rows = 128 rows
      int row = seg * 8 + srow;
      gll16(A + (long)(bm * 128 + row) * K + kk + scol, As + seg * 512);
      gll16(BT + (long)(bn * 128 + row) * K + kk + scol, Bs + seg * 512);
    }
    __syncthreads();  // drains vmcnt for global_load_lds + barrier

#pragma unroll
    for (int kc = 0; kc < 2; kc++) {
      const int rq = (((kc * 4 + quad) ^ (l16 & 7)) * 8);  // un-swizzle for reader
      bf16x8 af[4], bfv[4];
#pragma unroll
      for (int mt = 0; mt < 4; mt++)
        af[mt] = *(const bf16x8*)(As + (wm * 64 + mt * 16 + l16) * 64 + rq);
#pragma unroll
      for (int nt = 0; nt < 4; nt++)
        bfv[nt] = *(const bf16x8*)(Bs + (wn * 64 + nt * 16 + l16) * 64 + rq);
#pragma unroll
      for (int mt = 0; mt < 4; mt++)
#pragma unroll
        for (int nt = 0; nt < 4; nt++)
          acc[mt][nt] = __builtin_amdgcn_mfma_f32_16x16x32_bf16(af[mt], bfv[nt], acc[mt][nt], 0, 0, 0);
    }
  }

  // epilogue: D elem (row = quad*4 + r, col = l16) within each 16x16 tile
#pragma unroll
  for (int mt = 0; mt < 4; mt++) {
#pragma unroll
    for (int nt = 0; nt < 4; nt++) {
      int row0 = bm * 128 + wm * 64 + mt * 16 + quad * 4;
      int col = bn * 128 + wn * 64 + nt * 16 + l16;
      if (F32OUT) {
        float* cp = (float*)Cv + (long)row0 * N + col;
#pragma unroll
        for (int r2 = 0; r2 < 4; r2++)
          cp[(long)r2 * N] = acc[mt][nt][r2];
      } else {
        unsigned short* cp = (unsigned short*)Cv + (long)row0 * N + col;
#pragma unroll
        for (int r2 = 0; r2 < 4; r2++)
          cp[(long)r2 * N] = f2b(acc[mt][nt][r2]);
      }
    }
  }
}

// ---------------------------------------------------------------------------
// Causal attention, one block per (b,h). QKV: [16384][1536] bf16.
// All 256 K-rows + V staged ONCE (one barrier), then wave w independently
// processes 32-row q-tile pair {w, 7-w}: (w+1)+(8-w) = 9 chunk-32s per wave.
// Kl: packed rows, global-side XOR swizzle (gll16-compatible). Vt: rows
// padded to 264 shorts. Pl: stride 40. Fixed-shift softmax (p = exp(s),
// fp32 row-sum normalize at end) — validated absmax 0.0156.
// ---------------------------------------------------------------------------
__global__ __launch_bounds__(256, 2) void attn(const unsigned short* __restrict__ QKV,
                                               unsigned short* __restrict__ AO) {
  const int bh = blockIdx.x;
  const int b = bh >> 3, h = bh & 7;
  const int tid = threadIdx.x;
  const int wave = tid >> 6, lane = tid & 63;
  const int quad = lane >> 4, l16 = lane & 15;

  __shared__ unsigned short Kl[256 * 64];    // [j][cg], stored cg holds global cg^(j&7)
  __shared__ unsigned short Vt[64 * 264];    // [d][j], padded rows
  __shared__ unsigned short Pl[4][32 * 40];  // per-wave P [trow][col], padded

  const unsigned short* Qb = QKV + (long)b * 256 * 1536 + h * 64;
  const unsigned short* Kb = Qb + 512;
  const unsigned short* Vb = Qb + 1024;

  // ---- stage K: 32 segs x 8 rows, gll16 with global-side swizzle ----
  {
    int r = lane >> 3, cg = lane & 7;
#pragma unroll
    for (int s = 0; s < 8; s++) {
      int seg = wave * 8 + s;
      gll16(Kb + (long)(seg * 8 + r) * 1536 + ((cg ^ r) * 8), Kl + seg * 512);
    }
  }
  // ---- stage V transposed: thread tid owns V row j=tid ----
  {
    int j = tid;
    const unsigned short* vp = Vb + (long)j * 1536;
#pragma unroll
    for (int g = 0; g < 8; g++) {
      union { u32x4 v; unsigned short s[8]; } d;
      d.v = *(const u32x4*)(vp + g * 8);
#pragma unroll
      for (int q = 0; q < 8; q++)
        Vt[(g * 8 + q) * 264 + j] = d.s[q];
    }
  }
  // ---- Q fragments for this wave's tile pair ----
  const int tiles[2] = {wave, 7 - wave};
  bf16x8 qf[2][2][2];  // [ti][kc][mt]
#pragma unroll
  for (int ti = 0; ti < 2; ti++)
#pragma unroll
    for (int kc = 0; kc < 2; kc++)
#pragma unroll
      for (int mt = 0; mt < 2; mt++)
        qf[ti][kc][mt] = *(const bf16x8*)(Qb +
            (long)(tiles[ti] * 32 + mt * 16 + l16) * 1536 + kc * 32 + quad * 8);

  __syncthreads();  // drains gll16 vmcnt + V/Q visibility; the ONLY barrier

  f32x4 O[2][2][4] = {};      // [ti][mt][dt]
  float lsum[2][2][4] = {};   // [ti][mt][r]
  const float scale = 0.044194173824159216f;  // 1/sqrt(512)

#pragma unroll
  for (int ti = 0; ti < 2; ti++) {
    const int t = tiles[ti];
    for (int c32 = 0; c32 <= t; c32++) {       // wave-uniform trip count
      // ---- S = Q K^T for 32 rows x 32 cols ----
      f32x4 S[2][2] = {};                      // [mt][st]
#pragma unroll
      for (int kc = 0; kc < 2; kc++) {
        bf16x8 kbf[2];
#pragma unroll
        for (int st = 0; st < 2; st++) {
          int jrow = c32 * 32 + st * 16 + l16;
          kbf[st] = *(const bf16x8*)(Kl + jrow * 64 + (((kc * 4 + quad) ^ (jrow & 7)) * 8));
        }
#pragma unroll
        for (int mt = 0; mt < 2; mt++)
#pragma unroll
          for (int st = 0; st < 2; st++)
            S[mt][st] = __builtin_amdgcn_mfma_f32_16x16x32_bf16(qf[ti][kc][mt], kbf[st], S[mt][st], 0, 0, 0);
      }
      // ---- softmax numerator, P -> LDS (C-layout -> row-major) ----
      const bool diag = (c32 == t);
#pragma unroll
      for (int mt = 0; mt < 2; mt++)
#pragma unroll
        for (int st = 0; st < 2; st++)
#pragma unroll
          for (int r = 0; r < 4; r++) {
            int trow = mt * 16 + quad * 4 + r;         // row within 32-row tile
            float p = __expf(S[mt][st][r] * scale);
            if (diag && (st * 16 + l16 > trow)) p = 0.0f;
            lsum[ti][mt][r] += p;
            Pl[wave][trow * 40 + st * 16 + l16] = f2b(p);
          }
      // ---- O += P V  (same-wave LDS RAW: compiler lgkmcnt, no barrier) ----
      bf16x8 pa[2], vbf[4];
#pragma unroll
      for (int mt = 0; mt < 2; mt++)
        pa[mt] = *(const bf16x8*)(&Pl[wave][(mt * 16 + l16) * 40 + quad * 8]);
#pragma unroll
      for (int dt = 0; dt < 4; dt++)
        vbf[dt] = *(const bf16x8*)(Vt + (dt * 16 + l16) * 264 + c32 * 32 + quad * 8);
#pragma unroll
      for (int mt = 0; mt < 2; mt++)
#pragma unroll
        for (int dt = 0; dt < 4; dt++)
          O[ti][mt][dt] = __builtin_amdgcn_mfma_f32_16x16x32_bf16(pa[mt], vbf[dt], O[ti][mt][dt], 0, 0, 0);
    }
  }

  // ---- normalize by row sum (16 lanes of a quad hold one row's 16 cols) ----
  float linv[2][2][4];
#pragma unroll
  for (int ti = 0; ti < 2; ti++)
#pragma unroll
    for (int mt = 0; mt < 2; mt++)
#pragma unroll
      for (int r = 0; r < 4; r++) {
        float s = lsum[ti][mt][r];
        s += __shfl_xor(s, 1); s += __shfl_xor(s, 2);
        s += __shfl_xor(s, 4); s += __shfl_xor(s, 8);
        linv[ti][mt][r] = 1.0f / s;
      }
#pragma unroll
  for (int ti = 0; ti < 2; ti++)
#pragma unroll
    for (int mt = 0; mt < 2; mt++)
#pragma unroll
      for (int dt = 0; dt < 4; dt++)
#pragma unroll
        for (int r = 0; r < 4; r++) {
          int t_ = tiles[ti] * 32 + mt * 16 + quad * 4 + r;
          int d = dt * 16 + l16;
          AO[(long)(b * 256 + t_) * 512 + h * 64 + d] = f2b(O[ti][mt][dt][r] * linv[ti][mt][r]);
        }
}

// ---------------------------------------------------------------------------
extern "C" void kernel_launch(void* const* d_in, const int* in_sizes, int n_in,
                              void* d_out, int out_size, void* d_ws, size_t ws_size,
                              hipStream_t stream) {
  const float* x  = (const float*)d_in[0];   // [16384][512] fp32
  const float* Wq = (const float*)d_in[1];   // [8][512][64] fp32
  const float* Wk = (const float*)d_in[2];
  const float* Wv = (const float*)d_in[3];
  const float* Wo = (const float*)d_in[4];   // [512][512] fp32

  unsigned short* Wt  = (unsigned short*)d_ws;                 // 1536*512
  unsigned short* WoT = Wt + 1536 * 512;                       // 512*512
  unsigned short* xb  = WoT + 512 * 512;                       // 16384*512
  unsigned short* QKV = xb + (long)16384 * 512;                // 16384*1536
  unsigned short* AO  = QKV + (long)16384 * 1536;              // 16384*512
  float* out = (float*)d_out;                                  // [16384][512] fp32

  prep<<<8448, 256, 0, stream>>>(x, Wq, Wk, Wv, Wo, xb, Wt, WoT);

  gemm_bt<0><<<1536, 256, 0, stream>>>(xb, Wt, (void*)QKV, 1536);

  attn<<<512, 256, 0, stream>>>(QKV, AO);

  gemm_bt<1><<<512, 256, 0, stream>>>(AO, WoT, (void*)out, 512);
}